// Round 26
// baseline (224.905 us; speedup 1.0000x reference)
//
#include <hip/hip_runtime.h>
#include <hip/hip_bf16.h>

// Swin3D MHSA: B=256 windows, N=392 tokens, DIM=128, H=4 heads, dh=32.
// R26: R25 with the correct fast-exp2 spelling: __builtin_amdgcn_exp2f
//      (bare v_exp_f32; "__exp2f" doesn't exist in HIP -> R25 compile fail).
//      q pre-scaled by 1/sqrt(32)*log2e, bias table by log2e; otherwise
//      byte-identical to R23 (prev best 144.9us).

typedef __attribute__((ext_vector_type(8))) short bf16x8;
typedef __attribute__((ext_vector_type(4))) float f32x4;
typedef __attribute__((ext_vector_type(4))) short s16x4;
typedef __attribute__((ext_vector_type(2))) unsigned int u32x2;

#define NTOK 392
#define NN (NTOK * NTOK)   // 153664
#define TABLE 2535         // 15*13*13
#define LOG2E 1.4426950408889634f
#define QSCALE (0.17677669529663689f * 1.4426950408889634f)  // 1/sqrt(32)*log2e

__device__ __forceinline__ unsigned short f2bf(float f) {
  union { float f; unsigned u; } v; v.f = f;
  unsigned r = v.u + 0x7FFFu + ((v.u >> 16) & 1u);
  return (unsigned short)(r >> 16);
}
__device__ __forceinline__ unsigned short f2bf_rn(float f) {
  union { __hip_bfloat16 h; unsigned short u; } v;
  v.h = __float2bfloat16(f);
  return v.u;
}
__device__ __forceinline__ float b2f(short s) {
  union { unsigned u; float f; } v;
  v.u = ((unsigned)(unsigned short)s) << 16;
  return v.f;
}
__device__ __forceinline__ unsigned pk2(float lo, float hi) {
  return (unsigned)f2bf_rn(lo) | ((unsigned)f2bf_rn(hi) << 16);
}
__device__ __forceinline__ float fexp2(float x) {   // bare v_exp_f32
  return __builtin_amdgcn_exp2f(x);
}

// ---------------- K1: bias lane-layout table (x log2e) + weight conversion --
__global__ __launch_bounds__(256) void pre_kernel(
    const float* __restrict__ rpb, const int* __restrict__ relidx,
    const float* __restrict__ Wqkv, const float* __restrict__ Wp,
    unsigned short* __restrict__ biaspre,
    unsigned short* __restrict__ wqbf, unsigned short* __restrict__ wpbf) {
  if (blockIdx.x < 2500) {  // bias table, pre-scaled by log2e for fexp2
    int g = blockIdx.x * 256 + threadIdx.x;  // 640000
    if (g >= 640000) return;
    int r = g & 3, lane = (g >> 2) & 63;
    int t = g >> 8;
    int jt = t % 25; int t2 = t / 25;
    int rb = t2 % 25; int h = t2 / 25;
    int q = rb * 16 + (lane & 15); if (q > 391) q = 391;
    int k = jt * 16 + (lane >> 4) * 4 + r; if (k > 391) k = 391;
    int f = q * (NTOK * 4) + k * 4 + h;   // raw (n,n,H) reshape quirk
    int hs = f / NN; int p = f - hs * NN;
    biaspre[g] = f2bf(rpb[hs * TABLE + relidx[p]] * LOG2E);
  } else {                  // weight f32 -> bf16
    int g = (blockIdx.x - 2500) * 256 + threadIdx.x;  // 16384 x 4 elems
    const float* src; unsigned short* dst; int off;
    if (g < 12288) { src = Wqkv; dst = wqbf; off = g * 4; }
    else           { src = Wp;   dst = wpbf; off = (g - 12288) * 4; }
    f32x4 v = *(const f32x4*)(src + off);
    s16x4 o;
    o[0] = (short)f2bf(v[0]); o[1] = (short)f2bf(v[1]);
    o[2] = (short)f2bf(v[2]); o[3] = (short)f2bf(v[3]);
    *(s16x4*)(dst + off) = o;
  }
}

// ---------------- K2: QKV GEMM — fused 3 slices, A staged once (R16) -------
__global__ __launch_bounds__(256, 2) void qkv_gemm(
    const float* __restrict__ hidden, const unsigned short* __restrict__ wqbf,
    const float* __restrict__ bqkv,
    unsigned short* __restrict__ qbuf, unsigned short* __restrict__ kbuf,
    unsigned short* __restrict__ vtbuf) {
  __shared__ unsigned short Afull[128][138];  // 35328 B
  __shared__ unsigned short Bbf[128][34];     // 8704 B
  __shared__ unsigned short Epi[128][132];    // 33792 B
  const int tid = threadIdx.x;
  const int w = tid >> 6, lane = tid & 63, l15 = lane & 15, lhi = lane >> 4;
  const int mblk = blockIdx.x;
  const int wm = w >> 1, wn = w & 1;

#pragma unroll
  for (int it = 0; it < 8; ++it) {
    int i = it * 256 + tid;            // 2048 chunks of 8 elems
    int row = i >> 4, c8 = i & 15;
    const float* ap = hidden + ((size_t)(mblk * 128 + row)) * 128 + c8 * 8;
    f32x4 lo = *(const f32x4*)ap;
    f32x4 hi = *(const f32x4*)(ap + 4);
    u32x2 p0; p0[0] = pk2(lo[0], lo[1]); p0[1] = pk2(lo[2], lo[3]);
    u32x2 p1; p1[0] = pk2(hi[0], hi[1]); p1[1] = pk2(hi[2], hi[3]);
    *(u32x2*)&Afull[row][c8 * 8] = p0;
    *(u32x2*)&Afull[row][c8 * 8 + 4] = p1;
  }

  for (int s = 0; s < 3; ++s) {
    f32x4 acc[4][4];
#pragma unroll
    for (int m = 0; m < 4; ++m)
#pragma unroll
      for (int n = 0; n < 4; ++n) acc[m][n] = 0.0f;

    for (int kk = 0; kk < 4; ++kk) {
      __syncthreads();
#pragma unroll
      for (int it = 0; it < 2; ++it) {
        int i = it * 256 + tid;
        int row = i >> 2, c = i & 3;
        *(bf16x8*)&Bbf[row][c * 8] = *(const bf16x8*)(
            wqbf + ((size_t)(s * 128 + row)) * 128 + kk * 32 + c * 8);
      }
      __syncthreads();
      bf16x8 af[4], bf[4];
#pragma unroll
      for (int m = 0; m < 4; ++m)
        af[m] = *(const bf16x8*)&Afull[wm * 64 + m * 16 + l15][kk * 32 + lhi * 8];
#pragma unroll
      for (int n = 0; n < 4; ++n)
        bf[n] = *(const bf16x8*)&Bbf[wn * 64 + n * 16 + l15][lhi * 8];
#pragma unroll
      for (int m = 0; m < 4; ++m)
#pragma unroll
        for (int n = 0; n < 4; ++n)
          acc[m][n] = __builtin_amdgcn_mfma_f32_16x16x32_bf16(af[m], bf[n], acc[m][n], 0, 0, 0);
    }

    float bias_n[4];
#pragma unroll
    for (int n = 0; n < 4; ++n) bias_n[n] = bqkv[s * 128 + wn * 64 + n * 16 + l15];

    if (s < 2) {
      const float mul = (s == 0) ? QSCALE : 1.0f;  // q carries log2e for fexp2
#pragma unroll
      for (int m = 0; m < 4; ++m)
#pragma unroll
        for (int n = 0; n < 4; ++n)
#pragma unroll
          for (int r = 0; r < 4; ++r)
            Epi[wm * 64 + m * 16 + lhi * 4 + r][wn * 64 + n * 16 + l15] =
                f2bf_rn((acc[m][n][r] + bias_n[n]) * mul);
      __syncthreads();
      unsigned short* dst = (s == 0) ? qbuf : kbuf;
#pragma unroll
      for (int it = 0; it < 8; ++it) {
        int idx = it * 256 + tid;
        int row = idx >> 4, c = idx & 15;
        *(bf16x8*)&dst[((size_t)(mblk * 128 + row)) * 128 + c * 8] =
            *(const bf16x8*)&Epi[row][c * 8];
      }
    } else {
#pragma unroll
      for (int m = 0; m < 4; ++m)
#pragma unroll
        for (int n = 0; n < 4; ++n)
#pragma unroll
          for (int r = 0; r < 4; ++r)
            Epi[wn * 64 + n * 16 + l15][wm * 64 + m * 16 + lhi * 4 + r] =
                f2bf_rn(acc[m][n][r] + bias_n[n]);
      __syncthreads();
#pragma unroll
      for (int it = 0; it < 8; ++it) {
        int idx = it * 256 + tid;
        int fe = idx >> 4, ch = idx & 15;
        int tg = mblk * 128 + ch * 8;   // 8-token chunk; 392%8==0 -> one window
        int wb = tg / 392;
        int n0 = tg - wb * 392;
        *(bf16x8*)&vtbuf[(((size_t)wb * 4 + (fe >> 5)) * 32 + (fe & 31)) * NTOK + n0] =
            *(const bf16x8*)&Epi[fe][ch * 8];
      }
    }
  }
}

// ---------------- K3: attention — R22/R23 body + builtin exp2 ---------------
__global__ __launch_bounds__(512, 2) void attn_kernel(
    const unsigned short* __restrict__ qbuf, const unsigned short* __restrict__ kbuf,
    const unsigned short* __restrict__ vtbuf, const unsigned short* __restrict__ biaspre,
    unsigned short* __restrict__ ctxbuf) {
  __shared__ unsigned short Ksh[400][40];   // 32000 B
  __shared__ unsigned int Psh[8][16][20];   // 10240 B -> 42.2 KB, 3 blk/CU

  const int tid = threadIdx.x;              // 0..511
  const int w = tid >> 6, lane = tid & 63;
  const int l15 = lane & 15, lhi = lane >> 4;
  const int bh = blockIdx.x;
  const int h = bh & 3, b = bh >> 2;
  const size_t vtb = (size_t)bh * (NTOK * 32);

  for (int i = tid; i < 3136; i += 512) {   // K from token-major (t,128)
    int row = i >> 3, c4 = i & 7;
    *(s16x4*)&Ksh[row][c4 * 4] =
        *(const s16x4*)(kbuf + ((size_t)(b * NTOK + row)) * 128 + h * 32 + c4 * 4);
  }
  if (tid < 256) { int row = 392 + (tid >> 5); Ksh[row][tid & 31] = 0; }  // pad
  __syncthreads();

  const unsigned short* vbase = vtbuf + vtb;
  const s16x4* bias_lane =
      (const s16x4*)(biaspre + (size_t)h * 25 * 25 * 256 + (size_t)lane * 4);

  // constant bf16 1.0 B-operand for rowsum MFMA
  bf16x8 ones;
#pragma unroll
  for (int i = 0; i < 8; ++i) ones[i] = (short)0x3F80;

  for (int rb = w; rb < 25; rb += 8) {
    int qrow = rb * 16 + l15; if (qrow > 391) qrow = 391;
    bf16x8 qf = *(const bf16x8*)(
        qbuf + ((size_t)(b * NTOK + qrow)) * 128 + h * 32 + lhi * 8);
    const s16x4* bp = bias_lane + (size_t)rb * 25 * 64;  // +jt*64 per jt

    f32x4 o0 = 0.0f, o1 = 0.0f, osum = 0.0f;

    // bias-only rotation: load g's vectors one iteration early
    s16x4 nbv0 = bp[0];
    s16x4 nbv1 = bp[64];

    for (int g = 0; g < 12; ++g) {  // jt pairs (2g, 2g+1), all k valid
      bf16x8 vf0 = *(const bf16x8*)(vbase + (size_t)l15 * NTOK + g * 32 + lhi * 8);
      bf16x8 vf1 = *(const bf16x8*)(vbase + (size_t)(16 + l15) * NTOK + g * 32 + lhi * 8);
      int jt0 = 2 * g, jt1 = 2 * g + 1;
      bf16x8 kf0 = *(const bf16x8*)&Ksh[jt0 * 16 + l15][lhi * 8];
      bf16x8 kf1 = *(const bf16x8*)&Ksh[jt1 * 16 + l15][lhi * 8];
      f32x4 s0 = __builtin_amdgcn_mfma_f32_16x16x32_bf16(kf0, qf, (f32x4)0.f, 0, 0, 0);
      f32x4 s1 = __builtin_amdgcn_mfma_f32_16x16x32_bf16(kf1, qf, (f32x4)0.f, 0, 0, 0);
      s16x4 bv0 = nbv0;
      s16x4 bv1 = nbv1;
      {  // prefetch next pair's bias (g=11 -> jt 24 / dup 24; tail uses nbv0)
        int jn0 = (2 * g + 2 < 25) ? (2 * g + 2) : 24;
        int jn1 = (2 * g + 3 < 25) ? (2 * g + 3) : 24;
        nbv0 = bp[jn0 * 64];
        nbv1 = bp[jn1 * 64];
      }
      float e00 = fexp2(s0[0] + b2f(bv0[0])), e01 = fexp2(s0[1] + b2f(bv0[1]));
      float e02 = fexp2(s0[2] + b2f(bv0[2])), e03 = fexp2(s0[3] + b2f(bv0[3]));
      float e10 = fexp2(s1[0] + b2f(bv1[0])), e11 = fexp2(s1[1] + b2f(bv1[1]));
      float e12 = fexp2(s1[2] + b2f(bv1[2])), e13 = fexp2(s1[3] + b2f(bv1[3]));
      u32x2 wlo; wlo[0] = pk2(e00, e01); wlo[1] = pk2(e02, e03);
      u32x2 whi; whi[0] = pk2(e10, e11); whi[1] = pk2(e12, e13);
      *(u32x2*)&Psh[w][l15][lhi * 2] = wlo;       // k cols lhi*4..+3
      *(u32x2*)&Psh[w][l15][8 + lhi * 2] = whi;   // k cols 16+lhi*4..+3
      bf16x8 pf = *(const bf16x8*)&Psh[w][l15][lhi * 4];
      o0 = __builtin_amdgcn_mfma_f32_16x16x32_bf16(pf, vf0, o0, 0, 0, 0);
      o1 = __builtin_amdgcn_mfma_f32_16x16x32_bf16(pf, vf1, o1, 0, 0, 0);
      osum = __builtin_amdgcn_mfma_f32_16x16x32_bf16(pf, ones, osum, 0, 0, 0);
    }
    {  // g = 12: jt0 = 24 (k 384..391 valid only for lhi<2), jt1 absent
      bf16x8 vf0 = *(const bf16x8*)(vbase + (size_t)l15 * NTOK + 384 + lhi * 8);
      bf16x8 vf1 = *(const bf16x8*)(vbase + (size_t)(16 + l15) * NTOK + 384 + lhi * 8);
      bf16x8 kf0 = *(const bf16x8*)&Ksh[384 + l15][lhi * 8];
      f32x4 s0 = __builtin_amdgcn_mfma_f32_16x16x32_bf16(kf0, qf, (f32x4)0.f, 0, 0, 0);
      s16x4 bv0 = nbv0;   // prefetched bp[24*64]
      float e00 = fexp2(s0[0] + b2f(bv0[0])), e01 = fexp2(s0[1] + b2f(bv0[1]));
      float e02 = fexp2(s0[2] + b2f(bv0[2])), e03 = fexp2(s0[3] + b2f(bv0[3]));
      if (lhi >= 2) { e00 = 0.f; e01 = 0.f; e02 = 0.f; e03 = 0.f; }
      u32x2 wlo; wlo[0] = pk2(e00, e01); wlo[1] = pk2(e02, e03);
      u32x2 whi; whi[0] = 0u; whi[1] = 0u;
      *(u32x2*)&Psh[w][l15][lhi * 2] = wlo;
      *(u32x2*)&Psh[w][l15][8 + lhi * 2] = whi;
      bf16x8 pf = *(const bf16x8*)&Psh[w][l15][lhi * 4];
      o0 = __builtin_amdgcn_mfma_f32_16x16x32_bf16(pf, vf0, o0, 0, 0, 0);
      o1 = __builtin_amdgcn_mfma_f32_16x16x32_bf16(pf, vf1, o1, 0, 0, 0);
      osum = __builtin_amdgcn_mfma_f32_16x16x32_bf16(pf, ones, osum, 0, 0, 0);
    }

    // rowsum arrived in output C-layout: normalize directly, no shuffles
#pragma unroll
    for (int r = 0; r < 4; ++r) {
      int row = rb * 16 + lhi * 4 + r;
      if (row < NTOK) {
        float rr = 1.f / osum[r];
        unsigned short* crow = ctxbuf + ((size_t)(b * NTOK) + row) * 128 + h * 32;
        crow[l15] = f2bf_rn(o0[r] * rr);
        crow[16 + l15] = f2bf_rn(o1[r] * rr);
      }
    }
  }
}

// ---------------- K4: proj GEMM — 128x128 tile, plain stores ---------------
__global__ __launch_bounds__(256, 4) void proj_gemm(
    const unsigned short* __restrict__ ctxbuf, const unsigned short* __restrict__ wpbf,
    const float* __restrict__ bp, float* __restrict__ out) {
  __shared__ unsigned short Abf[128][34];
  __shared__ unsigned short Bbf[128][34];
  const int tid = threadIdx.x;
  const int w = tid >> 6, lane = tid & 63, l15 = lane & 15, lhi = lane >> 4;
  const int mblk = blockIdx.x;
  const int wm = w >> 1, wn = w & 1;

  f32x4 acc[4][4];
#pragma unroll
  for (int m = 0; m < 4; ++m)
#pragma unroll
    for (int n = 0; n < 4; ++n) acc[m][n] = 0.0f;

  for (int kk = 0; kk < 4; ++kk) {
#pragma unroll
    for (int it = 0; it < 2; ++it) {
      int i = it * 256 + tid;
      int row = i >> 2, c = i & 3;
      *(bf16x8*)&Abf[row][c * 8] = *(const bf16x8*)(
          ctxbuf + ((size_t)(mblk * 128 + row)) * 128 + kk * 32 + c * 8);
      *(bf16x8*)&Bbf[row][c * 8] = *(const bf16x8*)(
          wpbf + ((size_t)row) * 128 + kk * 32 + c * 8);
    }
    __syncthreads();
    bf16x8 af[4], bf[4];
#pragma unroll
    for (int m = 0; m < 4; ++m) af[m] = *(const bf16x8*)&Abf[wm * 64 + m * 16 + l15][lhi * 8];
#pragma unroll
    for (int n = 0; n < 4; ++n) bf[n] = *(const bf16x8*)&Bbf[wn * 64 + n * 16 + l15][lhi * 8];
#pragma unroll
    for (int m = 0; m < 4; ++m)
#pragma unroll
      for (int n = 0; n < 4; ++n)
        acc[m][n] = __builtin_amdgcn_mfma_f32_16x16x32_bf16(af[m], bf[n], acc[m][n], 0, 0, 0);
    __syncthreads();
  }

  float bias_n[4];
#pragma unroll
  for (int n = 0; n < 4; ++n) bias_n[n] = bp[wn * 64 + n * 16 + l15];
#pragma unroll
  for (int m = 0; m < 4; ++m)
#pragma unroll
    for (int n = 0; n < 4; ++n)
#pragma unroll
      for (int r = 0; r < 4; ++r) {
        int row = mblk * 128 + wm * 64 + m * 16 + lhi * 4 + r;
        out[(size_t)row * 128 + wn * 64 + n * 16 + l15] = acc[m][n][r] + bias_n[n];
      }
}

// ---------------- launch ----------------
extern "C" void kernel_launch(void* const* d_in, const int* in_sizes, int n_in,
                              void* d_out, int out_size, void* d_ws, size_t ws_size,
                              hipStream_t stream) {
  const float* hidden = (const float*)d_in[0];
  const float* Wqkv = (const float*)d_in[1];
  const float* bqkv = (const float*)d_in[2];
  const float* Wp = (const float*)d_in[3];
  const float* bp = (const float*)d_in[4];
  const float* rpb = (const float*)d_in[5];
  const int* relidx = (const int*)d_in[6];

  // ws: q | k | vt(+pad) | ctx (bf16, 12,845,056 each) | biaspre bf16 | weights
  unsigned short* qbuf = (unsigned short*)d_ws;
  unsigned short* kbuf = qbuf + 12845056;
  unsigned short* vtbuf = kbuf + 12845056;
  unsigned short* ctxbuf = vtbuf + 12845056 + 1024;  // pad: attn V reads overshoot
  unsigned short* biaspre = ctxbuf + 12845056;
  unsigned short* wqbf = biaspre + 640000;
  unsigned short* wpbf = wqbf + 49152;

  pre_kernel<<<2564, 256, 0, stream>>>(rpb, relidx, Wqkv, Wp, biaspre, wqbf, wpbf);
  qkv_gemm<<<784, 256, 0, stream>>>(hidden, wqbf, bqkv, qbuf, kbuf, vtbuf);
  attn_kernel<<<1024, 512, 0, stream>>>(qbuf, kbuf, vtbuf, biaspre, ctxbuf);
  proj_gemm<<<784, 256, 0, stream>>>(ctxbuf, wpbf, bp, (float*)d_out);
}

// Round 27
// 144.489 us; speedup vs baseline: 1.5566x; 1.5566x over previous
//
#include <hip/hip_runtime.h>
#include <hip/hip_bf16.h>

// Swin3D MHSA: B=256 windows, N=392 tokens, DIM=128, H=4 heads, dh=32.
// FINAL (R23 revert): session best 144.9us (from 281us baseline).
//   pre_kernel: bias in MFMA lane layout (bf16) + weight f32->bf16, merged.
//   qkv_gemm: 128x128-tile MFMA GEMM, 3 W-slices fused, A staged to LDS once,
//             LDS-transpose epilogues (q/k token-major, v feature-major).
//   attn: swapped-QK^T, K in LDS, coalesced 16B V loads, Psh P-relayout,
//         bias 1-ahead prefetch, MFMA-ones rowsum, 512thr/(512,2) = 24 w/CU.
//   proj_gemm: 128x128-tile MFMA GEMM, plain f32 stores (NT hint hurt).
// Exp2-fold attempts (R24 libm exp2f, R26 builtin) both regressed via
// VALU-guards / VGPR-plan changes -- __expf is optimal here.

typedef __attribute__((ext_vector_type(8))) short bf16x8;
typedef __attribute__((ext_vector_type(4))) float f32x4;
typedef __attribute__((ext_vector_type(4))) short s16x4;
typedef __attribute__((ext_vector_type(2))) unsigned int u32x2;

#define NTOK 392
#define NN (NTOK * NTOK)   // 153664
#define TABLE 2535         // 15*13*13
#define SCALE 0.17677669529663689f  // 1/sqrt(32)

__device__ __forceinline__ unsigned short f2bf(float f) {
  union { float f; unsigned u; } v; v.f = f;
  unsigned r = v.u + 0x7FFFu + ((v.u >> 16) & 1u);
  return (unsigned short)(r >> 16);
}
__device__ __forceinline__ unsigned short f2bf_rn(float f) {
  union { __hip_bfloat16 h; unsigned short u; } v;
  v.h = __float2bfloat16(f);
  return v.u;
}
__device__ __forceinline__ float b2f(short s) {
  union { unsigned u; float f; } v;
  v.u = ((unsigned)(unsigned short)s) << 16;
  return v.f;
}
__device__ __forceinline__ unsigned pk2(float lo, float hi) {
  return (unsigned)f2bf_rn(lo) | ((unsigned)f2bf_rn(hi) << 16);
}

// ---------------- K1: bias lane-layout table + weight conversion (merged) ---
__global__ __launch_bounds__(256) void pre_kernel(
    const float* __restrict__ rpb, const int* __restrict__ relidx,
    const float* __restrict__ Wqkv, const float* __restrict__ Wp,
    unsigned short* __restrict__ biaspre,
    unsigned short* __restrict__ wqbf, unsigned short* __restrict__ wpbf) {
  if (blockIdx.x < 2500) {  // bias table
    int g = blockIdx.x * 256 + threadIdx.x;  // 640000
    if (g >= 640000) return;
    int r = g & 3, lane = (g >> 2) & 63;
    int t = g >> 8;
    int jt = t % 25; int t2 = t / 25;
    int rb = t2 % 25; int h = t2 / 25;
    int q = rb * 16 + (lane & 15); if (q > 391) q = 391;
    int k = jt * 16 + (lane >> 4) * 4 + r; if (k > 391) k = 391;
    int f = q * (NTOK * 4) + k * 4 + h;   // raw (n,n,H) reshape quirk
    int hs = f / NN; int p = f - hs * NN;
    biaspre[g] = f2bf(rpb[hs * TABLE + relidx[p]]);
  } else {                  // weight f32 -> bf16
    int g = (blockIdx.x - 2500) * 256 + threadIdx.x;  // 16384 x 4 elems
    const float* src; unsigned short* dst; int off;
    if (g < 12288) { src = Wqkv; dst = wqbf; off = g * 4; }
    else           { src = Wp;   dst = wpbf; off = (g - 12288) * 4; }
    f32x4 v = *(const f32x4*)(src + off);
    s16x4 o;
    o[0] = (short)f2bf(v[0]); o[1] = (short)f2bf(v[1]);
    o[2] = (short)f2bf(v[2]); o[3] = (short)f2bf(v[3]);
    *(s16x4*)(dst + off) = o;
  }
}

// ---------------- K2: QKV GEMM — fused 3 slices, A staged once -------------
__global__ __launch_bounds__(256, 2) void qkv_gemm(
    const float* __restrict__ hidden, const unsigned short* __restrict__ wqbf,
    const float* __restrict__ bqkv,
    unsigned short* __restrict__ qbuf, unsigned short* __restrict__ kbuf,
    unsigned short* __restrict__ vtbuf) {
  __shared__ unsigned short Afull[128][138];  // 35328 B
  __shared__ unsigned short Bbf[128][34];     // 8704 B
  __shared__ unsigned short Epi[128][132];    // 33792 B
  const int tid = threadIdx.x;
  const int w = tid >> 6, lane = tid & 63, l15 = lane & 15, lhi = lane >> 4;
  const int mblk = blockIdx.x;
  const int wm = w >> 1, wn = w & 1;

#pragma unroll
  for (int it = 0; it < 8; ++it) {
    int i = it * 256 + tid;            // 2048 chunks of 8 elems
    int row = i >> 4, c8 = i & 15;
    const float* ap = hidden + ((size_t)(mblk * 128 + row)) * 128 + c8 * 8;
    f32x4 lo = *(const f32x4*)ap;
    f32x4 hi = *(const f32x4*)(ap + 4);
    u32x2 p0; p0[0] = pk2(lo[0], lo[1]); p0[1] = pk2(lo[2], lo[3]);
    u32x2 p1; p1[0] = pk2(hi[0], hi[1]); p1[1] = pk2(hi[2], hi[3]);
    *(u32x2*)&Afull[row][c8 * 8] = p0;
    *(u32x2*)&Afull[row][c8 * 8 + 4] = p1;
  }

  for (int s = 0; s < 3; ++s) {
    f32x4 acc[4][4];
#pragma unroll
    for (int m = 0; m < 4; ++m)
#pragma unroll
      for (int n = 0; n < 4; ++n) acc[m][n] = 0.0f;

    for (int kk = 0; kk < 4; ++kk) {
      __syncthreads();
#pragma unroll
      for (int it = 0; it < 2; ++it) {
        int i = it * 256 + tid;
        int row = i >> 2, c = i & 3;
        *(bf16x8*)&Bbf[row][c * 8] = *(const bf16x8*)(
            wqbf + ((size_t)(s * 128 + row)) * 128 + kk * 32 + c * 8);
      }
      __syncthreads();
      bf16x8 af[4], bf[4];
#pragma unroll
      for (int m = 0; m < 4; ++m)
        af[m] = *(const bf16x8*)&Afull[wm * 64 + m * 16 + l15][kk * 32 + lhi * 8];
#pragma unroll
      for (int n = 0; n < 4; ++n)
        bf[n] = *(const bf16x8*)&Bbf[wn * 64 + n * 16 + l15][lhi * 8];
#pragma unroll
      for (int m = 0; m < 4; ++m)
#pragma unroll
        for (int n = 0; n < 4; ++n)
          acc[m][n] = __builtin_amdgcn_mfma_f32_16x16x32_bf16(af[m], bf[n], acc[m][n], 0, 0, 0);
    }

    float bias_n[4];
#pragma unroll
    for (int n = 0; n < 4; ++n) bias_n[n] = bqkv[s * 128 + wn * 64 + n * 16 + l15];

    if (s < 2) {
      const float mul = (s == 0) ? SCALE : 1.0f;
#pragma unroll
      for (int m = 0; m < 4; ++m)
#pragma unroll
        for (int n = 0; n < 4; ++n)
#pragma unroll
          for (int r = 0; r < 4; ++r)
            Epi[wm * 64 + m * 16 + lhi * 4 + r][wn * 64 + n * 16 + l15] =
                f2bf_rn((acc[m][n][r] + bias_n[n]) * mul);
      __syncthreads();
      unsigned short* dst = (s == 0) ? qbuf : kbuf;
#pragma unroll
      for (int it = 0; it < 8; ++it) {
        int idx = it * 256 + tid;
        int row = idx >> 4, c = idx & 15;
        *(bf16x8*)&dst[((size_t)(mblk * 128 + row)) * 128 + c * 8] =
            *(const bf16x8*)&Epi[row][c * 8];
      }
    } else {
#pragma unroll
      for (int m = 0; m < 4; ++m)
#pragma unroll
        for (int n = 0; n < 4; ++n)
#pragma unroll
          for (int r = 0; r < 4; ++r)
            Epi[wn * 64 + n * 16 + l15][wm * 64 + m * 16 + lhi * 4 + r] =
                f2bf_rn(acc[m][n][r] + bias_n[n]);
      __syncthreads();
#pragma unroll
      for (int it = 0; it < 8; ++it) {
        int idx = it * 256 + tid;
        int fe = idx >> 4, ch = idx & 15;
        int tg = mblk * 128 + ch * 8;   // 8-token chunk; 392%8==0 -> one window
        int wb = tg / 392;
        int n0 = tg - wb * 392;
        *(bf16x8*)&vtbuf[(((size_t)wb * 4 + (fe >> 5)) * 32 + (fe & 31)) * NTOK + n0] =
            *(const bf16x8*)&Epi[fe][ch * 8];
      }
    }
  }
}

// ---------------- K3: attention — 8 waves, (512,2), MFMA rowsum -------------
__global__ __launch_bounds__(512, 2) void attn_kernel(
    const unsigned short* __restrict__ qbuf, const unsigned short* __restrict__ kbuf,
    const unsigned short* __restrict__ vtbuf, const unsigned short* __restrict__ biaspre,
    unsigned short* __restrict__ ctxbuf) {
  __shared__ unsigned short Ksh[400][40];   // 32000 B
  __shared__ unsigned int Psh[8][16][20];   // 10240 B -> 42.2 KB, 3 blk/CU

  const int tid = threadIdx.x;              // 0..511
  const int w = tid >> 6, lane = tid & 63;
  const int l15 = lane & 15, lhi = lane >> 4;
  const int bh = blockIdx.x;
  const int h = bh & 3, b = bh >> 2;
  const size_t vtb = (size_t)bh * (NTOK * 32);

  for (int i = tid; i < 3136; i += 512) {   // K from token-major (t,128)
    int row = i >> 3, c4 = i & 7;
    *(s16x4*)&Ksh[row][c4 * 4] =
        *(const s16x4*)(kbuf + ((size_t)(b * NTOK + row)) * 128 + h * 32 + c4 * 4);
  }
  if (tid < 256) { int row = 392 + (tid >> 5); Ksh[row][tid & 31] = 0; }  // pad
  __syncthreads();

  const unsigned short* vbase = vtbuf + vtb;
  const s16x4* bias_lane =
      (const s16x4*)(biaspre + (size_t)h * 25 * 25 * 256 + (size_t)lane * 4);

  // constant bf16 1.0 B-operand for rowsum MFMA
  bf16x8 ones;
#pragma unroll
  for (int i = 0; i < 8; ++i) ones[i] = (short)0x3F80;

  for (int rb = w; rb < 25; rb += 8) {
    int qrow = rb * 16 + l15; if (qrow > 391) qrow = 391;
    bf16x8 qf = *(const bf16x8*)(
        qbuf + ((size_t)(b * NTOK + qrow)) * 128 + h * 32 + lhi * 8);
    const s16x4* bp = bias_lane + (size_t)rb * 25 * 64;  // +jt*64 per jt

    f32x4 o0 = 0.0f, o1 = 0.0f, osum = 0.0f;

    // bias-only rotation: load g's vectors one iteration early
    s16x4 nbv0 = bp[0];
    s16x4 nbv1 = bp[64];

    for (int g = 0; g < 12; ++g) {  // jt pairs (2g, 2g+1), all k valid
      bf16x8 vf0 = *(const bf16x8*)(vbase + (size_t)l15 * NTOK + g * 32 + lhi * 8);
      bf16x8 vf1 = *(const bf16x8*)(vbase + (size_t)(16 + l15) * NTOK + g * 32 + lhi * 8);
      int jt0 = 2 * g, jt1 = 2 * g + 1;
      bf16x8 kf0 = *(const bf16x8*)&Ksh[jt0 * 16 + l15][lhi * 8];
      bf16x8 kf1 = *(const bf16x8*)&Ksh[jt1 * 16 + l15][lhi * 8];
      f32x4 s0 = __builtin_amdgcn_mfma_f32_16x16x32_bf16(kf0, qf, (f32x4)0.f, 0, 0, 0);
      f32x4 s1 = __builtin_amdgcn_mfma_f32_16x16x32_bf16(kf1, qf, (f32x4)0.f, 0, 0, 0);
      s16x4 bv0 = nbv0;
      s16x4 bv1 = nbv1;
      {  // prefetch next pair's bias (g=11 -> jt 24 / dup 24; tail uses nbv0)
        int jn0 = (2 * g + 2 < 25) ? (2 * g + 2) : 24;
        int jn1 = (2 * g + 3 < 25) ? (2 * g + 3) : 24;
        nbv0 = bp[jn0 * 64];
        nbv1 = bp[jn1 * 64];
      }
      float e00 = __expf(s0[0] + b2f(bv0[0])), e01 = __expf(s0[1] + b2f(bv0[1]));
      float e02 = __expf(s0[2] + b2f(bv0[2])), e03 = __expf(s0[3] + b2f(bv0[3]));
      float e10 = __expf(s1[0] + b2f(bv1[0])), e11 = __expf(s1[1] + b2f(bv1[1]));
      float e12 = __expf(s1[2] + b2f(bv1[2])), e13 = __expf(s1[3] + b2f(bv1[3]));
      u32x2 wlo; wlo[0] = pk2(e00, e01); wlo[1] = pk2(e02, e03);
      u32x2 whi; whi[0] = pk2(e10, e11); whi[1] = pk2(e12, e13);
      *(u32x2*)&Psh[w][l15][lhi * 2] = wlo;       // k cols lhi*4..+3
      *(u32x2*)&Psh[w][l15][8 + lhi * 2] = whi;   // k cols 16+lhi*4..+3
      bf16x8 pf = *(const bf16x8*)&Psh[w][l15][lhi * 4];
      o0 = __builtin_amdgcn_mfma_f32_16x16x32_bf16(pf, vf0, o0, 0, 0, 0);
      o1 = __builtin_amdgcn_mfma_f32_16x16x32_bf16(pf, vf1, o1, 0, 0, 0);
      osum = __builtin_amdgcn_mfma_f32_16x16x32_bf16(pf, ones, osum, 0, 0, 0);
    }
    {  // g = 12: jt0 = 24 (k 384..391 valid only for lhi<2), jt1 absent
      bf16x8 vf0 = *(const bf16x8*)(vbase + (size_t)l15 * NTOK + 384 + lhi * 8);
      bf16x8 vf1 = *(const bf16x8*)(vbase + (size_t)(16 + l15) * NTOK + 384 + lhi * 8);
      bf16x8 kf0 = *(const bf16x8*)&Ksh[384 + l15][lhi * 8];
      f32x4 s0 = __builtin_amdgcn_mfma_f32_16x16x32_bf16(kf0, qf, (f32x4)0.f, 0, 0, 0);
      s16x4 bv0 = nbv0;   // prefetched bp[24*64]
      float e00 = __expf(s0[0] + b2f(bv0[0])), e01 = __expf(s0[1] + b2f(bv0[1]));
      float e02 = __expf(s0[2] + b2f(bv0[2])), e03 = __expf(s0[3] + b2f(bv0[3]));
      if (lhi >= 2) { e00 = 0.f; e01 = 0.f; e02 = 0.f; e03 = 0.f; }
      u32x2 wlo; wlo[0] = pk2(e00, e01); wlo[1] = pk2(e02, e03);
      u32x2 whi; whi[0] = 0u; whi[1] = 0u;
      *(u32x2*)&Psh[w][l15][lhi * 2] = wlo;
      *(u32x2*)&Psh[w][l15][8 + lhi * 2] = whi;
      bf16x8 pf = *(const bf16x8*)&Psh[w][l15][lhi * 4];
      o0 = __builtin_amdgcn_mfma_f32_16x16x32_bf16(pf, vf0, o0, 0, 0, 0);
      o1 = __builtin_amdgcn_mfma_f32_16x16x32_bf16(pf, vf1, o1, 0, 0, 0);
      osum = __builtin_amdgcn_mfma_f32_16x16x32_bf16(pf, ones, osum, 0, 0, 0);
    }

    // rowsum arrived in output C-layout: normalize directly, no shuffles
#pragma unroll
    for (int r = 0; r < 4; ++r) {
      int row = rb * 16 + lhi * 4 + r;
      if (row < NTOK) {
        float rr = 1.f / osum[r];
        unsigned short* crow = ctxbuf + ((size_t)(b * NTOK) + row) * 128 + h * 32;
        crow[l15] = f2bf_rn(o0[r] * rr);
        crow[16 + l15] = f2bf_rn(o1[r] * rr);
      }
    }
  }
}

// ---------------- K4: proj GEMM — 128x128 tile, plain stores ---------------
__global__ __launch_bounds__(256, 4) void proj_gemm(
    const unsigned short* __restrict__ ctxbuf, const unsigned short* __restrict__ wpbf,
    const float* __restrict__ bp, float* __restrict__ out) {
  __shared__ unsigned short Abf[128][34];
  __shared__ unsigned short Bbf[128][34];
  const int tid = threadIdx.x;
  const int w = tid >> 6, lane = tid & 63, l15 = lane & 15, lhi = lane >> 4;
  const int mblk = blockIdx.x;
  const int wm = w >> 1, wn = w & 1;

  f32x4 acc[4][4];
#pragma unroll
  for (int m = 0; m < 4; ++m)
#pragma unroll
    for (int n = 0; n < 4; ++n) acc[m][n] = 0.0f;

  for (int kk = 0; kk < 4; ++kk) {
#pragma unroll
    for (int it = 0; it < 2; ++it) {
      int i = it * 256 + tid;
      int row = i >> 2, c = i & 3;
      *(bf16x8*)&Abf[row][c * 8] = *(const bf16x8*)(
          ctxbuf + ((size_t)(mblk * 128 + row)) * 128 + kk * 32 + c * 8);
      *(bf16x8*)&Bbf[row][c * 8] = *(const bf16x8*)(
          wpbf + ((size_t)row) * 128 + kk * 32 + c * 8);
    }
    __syncthreads();
    bf16x8 af[4], bf[4];
#pragma unroll
    for (int m = 0; m < 4; ++m) af[m] = *(const bf16x8*)&Abf[wm * 64 + m * 16 + l15][lhi * 8];
#pragma unroll
    for (int n = 0; n < 4; ++n) bf[n] = *(const bf16x8*)&Bbf[wn * 64 + n * 16 + l15][lhi * 8];
#pragma unroll
    for (int m = 0; m < 4; ++m)
#pragma unroll
      for (int n = 0; n < 4; ++n)
        acc[m][n] = __builtin_amdgcn_mfma_f32_16x16x32_bf16(af[m], bf[n], acc[m][n], 0, 0, 0);
    __syncthreads();
  }

  float bias_n[4];
#pragma unroll
  for (int n = 0; n < 4; ++n) bias_n[n] = bp[wn * 64 + n * 16 + l15];
#pragma unroll
  for (int m = 0; m < 4; ++m)
#pragma unroll
    for (int n = 0; n < 4; ++n)
#pragma unroll
      for (int r = 0; r < 4; ++r) {
        int row = mblk * 128 + wm * 64 + m * 16 + lhi * 4 + r;
        out[(size_t)row * 128 + wn * 64 + n * 16 + l15] = acc[m][n][r] + bias_n[n];
      }
}

// ---------------- launch ----------------
extern "C" void kernel_launch(void* const* d_in, const int* in_sizes, int n_in,
                              void* d_out, int out_size, void* d_ws, size_t ws_size,
                              hipStream_t stream) {
  const float* hidden = (const float*)d_in[0];
  const float* Wqkv = (const float*)d_in[1];
  const float* bqkv = (const float*)d_in[2];
  const float* Wp = (const float*)d_in[3];
  const float* bp = (const float*)d_in[4];
  const float* rpb = (const float*)d_in[5];
  const int* relidx = (const int*)d_in[6];

  // ws: q | k | vt(+pad) | ctx (bf16, 12,845,056 each) | biaspre bf16 | weights
  unsigned short* qbuf = (unsigned short*)d_ws;
  unsigned short* kbuf = qbuf + 12845056;
  unsigned short* vtbuf = kbuf + 12845056;
  unsigned short* ctxbuf = vtbuf + 12845056 + 1024;  // pad: attn V reads overshoot
  unsigned short* biaspre = ctxbuf + 12845056;
  unsigned short* wqbf = biaspre + 640000;
  unsigned short* wpbf = wqbf + 49152;

  pre_kernel<<<2564, 256, 0, stream>>>(rpb, relidx, Wqkv, Wp, biaspre, wqbf, wpbf);
  qkv_gemm<<<784, 256, 0, stream>>>(hidden, wqbf, bqkv, qbuf, kbuf, vtbuf);
  attn_kernel<<<1024, 512, 0, stream>>>(qbuf, kbuf, vtbuf, biaspre, ctxbuf);
  proj_gemm<<<784, 256, 0, stream>>>(ctxbuf, wpbf, bp, (float*)d_out);
}